// Round 9
// baseline (2015.244 us; speedup 1.0000x reference)
//
#include <hip/hip_runtime.h>
#include <stdint.h>

// Problem constants (GRU_12764642803875)
#define Bsz 8
#define Ssz 1024
#define STATEsz 1024
#define Hsz 8
#define Dsz 128

typedef float  f32x4  __attribute__((ext_vector_type(4)));
typedef float  f32x2  __attribute__((ext_vector_type(2)));
typedef int    i32x4  __attribute__((ext_vector_type(4)));
typedef __bf16 bf16x8 __attribute__((ext_vector_type(8)));

__device__ __forceinline__ unsigned short f2bf(float f){
  unsigned int u = __float_as_uint(f);
  u = u + 0x7FFFu + ((u >> 16) & 1u);   // round-to-nearest-even
  return (unsigned short)(u >> 16);
}
__device__ __forceinline__ float bf2f(unsigned short s){
  return __uint_as_float(((unsigned int)s) << 16);
}
__device__ __forceinline__ float sigmoid_(float x){ return 1.f/(1.f+__expf(-x)); }
__device__ __forceinline__ float tanh_(float x){ return 2.f/(1.f+__expf(-2.f*x)) - 1.f; }

#define MFMA16(a,b,c) __builtin_amdgcn_mfma_f32_16x16x32_bf16((a),(b),(c),0,0,0)

// ---------------- fp32 -> bf16 cast, 4-wide ----------------
__global__ void k_cast_bf16(const float* __restrict__ in, unsigned short* __restrict__ out, int n4){
  int i = blockIdx.x*blockDim.x + threadIdx.x;
  if (i >= n4) return;
  f32x4 v = ((const f32x4*)in)[i];
  ushort4 o;
  o.x = f2bf(v[0]); o.y = f2bf(v[1]); o.z = f2bf(v[2]); o.w = f2bf(v[3]);
  ((ushort4*)out)[i] = o;
}

// ---------------- fp32 [R][C] -> bf16 [C][R] transpose ----------------
__global__ void k_transpose_bf16(const float* __restrict__ in, unsigned short* __restrict__ out, int R, int C){
  __shared__ float tile[32][33];
  int c0 = blockIdx.x*32, r0 = blockIdx.y*32;
  int tx = threadIdx.x, ty = threadIdx.y;   // block (32,8)
  #pragma unroll
  for (int i=0;i<4;++i) tile[ty+8*i][tx] = in[(size_t)(r0+ty+8*i)*C + c0+tx];
  __syncthreads();
  #pragma unroll
  for (int i=0;i<4;++i) out[(size_t)(c0+ty+8*i)*R + r0+tx] = f2bf(tile[tx][ty+8*i]);
}

// ---------------- bf16 MFMA GEMM: C[M,N] = A[M,K] @ Bt[N,K]^T (+bias) ----------------
// MODE 0: f32 C row-major.  MODE 1: bf16 C row-major.
// MODE 2: bf16 scatter into projT[h][t][g][d][b] (N must be 3072, M = B*S).
template<int MODE, bool BIAS>
__global__ __launch_bounds__(256) void k_gemm(
    const unsigned short* __restrict__ A, const unsigned short* __restrict__ Bt,
    const float* __restrict__ bias, unsigned short* __restrict__ Cb, float* __restrict__ Cf,
    int M, int N, int K){
  __shared__ unsigned short As[128][40];
  __shared__ unsigned short Bs[128][40];
  int t = threadIdx.x;
  int l = t & 63, w = t >> 6, wm = w >> 1, wn = w & 1;
  int m0 = blockIdx.y*128, n0 = blockIdx.x*128;
  f32x4 acc[4][4];
  #pragma unroll
  for(int a=0;a<4;++a)
    #pragma unroll
    for(int b=0;b<4;++b){ acc[a][b][0]=0.f; acc[a][b][1]=0.f; acc[a][b][2]=0.f; acc[a][b][3]=0.f; }
  int lr = l & 15, lk = (l >> 4)*8;
  for(int k0=0;k0<K;k0+=32){
    #pragma unroll
    for(int it=0; it<2; ++it){              // stage 128x32 bf16 for A and Bt
      int idx = t + 256*it, r = idx>>2, q = idx&3;
      i32x4 av = *(const i32x4*)(A  + (size_t)(m0+r)*K + k0 + q*8);
      i32x4 bv = *(const i32x4*)(Bt + (size_t)(n0+r)*K + k0 + q*8);
      *(i32x4*)(&As[r][q*8]) = av;
      *(i32x4*)(&Bs[r][q*8]) = bv;
    }
    __syncthreads();
    bf16x8 af[4], bfv[4];
    #pragma unroll
    for(int mi=0;mi<4;++mi) af[mi]  = *(const bf16x8*)(&As[wm*64+mi*16+lr][lk]);
    #pragma unroll
    for(int ni=0;ni<4;++ni) bfv[ni] = *(const bf16x8*)(&Bs[wn*64+ni*16+lr][lk]);
    #pragma unroll
    for(int mi=0;mi<4;++mi)
      #pragma unroll
      for(int ni=0;ni<4;++ni)
        acc[mi][ni] = MFMA16(af[mi], bfv[ni], acc[mi][ni]);
    __syncthreads();
  }
  // C/D layout: col = lane&15, row = (lane>>4)*4 + j  [m89-verified]
  int cr0 = (l>>4)*4;
  #pragma unroll
  for(int mi=0;mi<4;++mi){
    #pragma unroll
    for(int ni=0;ni<4;++ni){
      int col = n0 + wn*64 + ni*16 + lr;
      float bv = BIAS ? bias[col] : 0.f;
      #pragma unroll
      for(int j=0;j<4;++j){
        int row = m0 + wm*64 + mi*16 + cr0 + j;
        float v = acc[mi][ni][j] + bv;
        if (MODE == 0) Cf[(size_t)row*N + col] = v;
        else if (MODE == 1) Cb[(size_t)row*N + col] = f2bf(v);
        else {
          int b = row >> 10, tt = row & 1023;
          int g = col >> 10, hh = (col >> 7) & 7, d = col & 127;
          size_t idx = ((size_t)(hh*1024 + tt)*3 + g)*1024 + d*8 + b;
          Cb[idx] = f2bf(v);
        }
      }
    }
  }
}

// ---------------- recurrence via MFMA: 8 blocks (one per head), 512 threads ----------------
// 8 waves (2/SIMD for VALU<->MFMA co-issue); wave w owns ntile w: col = 16w + lr.
// M=16 rows = 8 batches + 8 pad. Per wave: 12 MFMA/step (4 aR + 4 aF + 4 aC),
// 4 sigmoid + 4 sigmoid + 4 tanh per lane. Gates loaded as dwordx2 from
// projT[h][t][g][d][b] (b fastest). 2 raw s_barriers/step with lgkmcnt(0) only.
__global__ __launch_bounds__(512, 1) void k_rnn_mfma(
    const unsigned short* __restrict__ projT,  // [8][1024][3][128][8] bf16
    const float* __restrict__ h0,
    const float* __restrict__ Wst, const float* __restrict__ Wfg, const float* __restrict__ Wrs,
    unsigned short* __restrict__ hs, float* __restrict__ hT){
  const int h = blockIdx.x;            // head
  const int t0 = threadIdx.x;
  const int l = t0 & 63, w = t0 >> 6;  // lane, wave (0..7)
  const int lr = l & 15;               // A-row / C-col (within tile)
  const int lg = l >> 4;               // quarter-wave group
  const int col = 16*w + lr;           // state column this wave's lane owns

  __shared__ unsigned short h_a[16][136];
  __shared__ unsigned short rh_a[16][136];

  // ---- weight B-frags: wbX[k][j] = W[32k+8lg+j][col] ----
  bf16x8 wbR[4], wbF[4], wbS[4];
  {
    const float* pR = Wrs + h*16384;
    const float* pF = Wfg + h*16384;
    const float* pS = Wst + h*16384;
    #pragma unroll
    for(int k=0;k<4;++k){
      #pragma unroll
      for(int j=0;j<8;++j){
        int din = 32*k + 8*lg + j;
        wbR[k][j] = (__bf16)pR[din*128 + col];
        wbF[k][j] = (__bf16)pF[din*128 + col];
        wbS[k][j] = (__bf16)pS[din*128 + col];
      }
    }
  }

  // ---- zero LDS (pad rows must stay 0), then init h ----
  for(int i=t0; i<16*136; i+=512){
    ((unsigned short*)h_a)[i] = 0;
    ((unsigned short*)rh_a)[i] = 0;
  }
  __syncthreads();
  float hc[4] = {0.f,0.f,0.f,0.f};
  if (lg < 2){
    #pragma unroll
    for(int j=0;j<4;++j){
      int b = 4*lg + j;
      hc[j] = h0[b*STATEsz + h*Dsz + col];
      h_a[b][col] = f2bf(hc[j]);
    }
  }

  // ---- depth-2 gate prefetch: per step 3 x dwordx2 (4 bf16 each, j=0..3) ----
  const unsigned short* pt0 = projT + (size_t)h*Ssz*3072 + col*8 + 4*lg;
  ushort4 zA={0,0,0,0}, fA={0,0,0,0}, rA={0,0,0,0};
  ushort4 zB={0,0,0,0}, fB={0,0,0,0}, rB={0,0,0,0};
  auto loadbuf = [&](int tt, ushort4 &z4, ushort4 &f4, ushort4 &r4){
    if (lg < 2 && tt < Ssz){
      const unsigned short* p = pt0 + (size_t)tt*3072;
      z4 = *(const ushort4*)(p + 0);
      f4 = *(const ushort4*)(p + 1024);
      r4 = *(const ushort4*)(p + 2048);
    }
  };
  loadbuf(0, zA, fA, rA);
  loadbuf(1, zB, fB, rB);
  __syncthreads();

  auto body = [&](int st, ushort4 &z4, ushort4 &f4, ushort4 &r4){
    // ---- phase 1: h A-frags + aR matvec (2+2 chains) ----
    bf16x8 af0 = *(const bf16x8*)(&h_a[lr][ 0 + 8*lg]);
    bf16x8 af1 = *(const bf16x8*)(&h_a[lr][32 + 8*lg]);
    bf16x8 af2 = *(const bf16x8*)(&h_a[lr][64 + 8*lg]);
    bf16x8 af3 = *(const bf16x8*)(&h_a[lr][96 + 8*lg]);
    const f32x4 z4v = {0.f,0.f,0.f,0.f};
    f32x4 aR0 = MFMA16(af0, wbR[0], z4v);
    f32x4 aR1 = MFMA16(af2, wbR[2], z4v);
    aR0 = MFMA16(af1, wbR[1], aR0);
    aR1 = MFMA16(af3, wbR[3], aR1);
    // r gate + rh publish (rows 0..7 only)
    unsigned short rr[4] = {r4.x, r4.y, r4.z, r4.w};
    float rv[4];
    #pragma unroll
    for(int j=0;j<4;++j) rv[j] = sigmoid_(bf2f(rr[j]) + aR0[j] + aR1[j]);
    if (lg < 2){
      #pragma unroll
      for(int j=0;j<4;++j) rh_a[4*lg+j][col] = f2bf(rv[j]*hc[j]);
    }
    asm volatile("s_waitcnt lgkmcnt(0)" ::: "memory");
    __builtin_amdgcn_s_barrier();
    asm volatile("" ::: "memory");
    // ---- phase 2: arf reads; aF (register inputs) issues under their latency ----
    bf16x8 ar0 = *(const bf16x8*)(&rh_a[lr][ 0 + 8*lg]);
    bf16x8 ar1 = *(const bf16x8*)(&rh_a[lr][32 + 8*lg]);
    bf16x8 ar2 = *(const bf16x8*)(&rh_a[lr][64 + 8*lg]);
    bf16x8 ar3 = *(const bf16x8*)(&rh_a[lr][96 + 8*lg]);
    f32x4 aF0 = MFMA16(af0, wbF[0], z4v);
    f32x4 aF1 = MFMA16(af2, wbF[2], z4v);
    aF0 = MFMA16(af1, wbF[1], aF0);
    aF1 = MFMA16(af3, wbF[3], aF1);
    f32x4 aC0 = MFMA16(ar0, wbS[0], z4v);
    f32x4 aC1 = MFMA16(ar2, wbS[2], z4v);
    aC0 = MFMA16(ar1, wbS[1], aC0);
    aC1 = MFMA16(ar3, wbS[3], aC1);
    // f, c, h update
    unsigned short zz[4] = {z4.x, z4.y, z4.z, z4.w};
    unsigned short ff[4] = {f4.x, f4.y, f4.z, f4.w};
    #pragma unroll
    for(int j=0;j<4;++j){
      float fj = sigmoid_(bf2f(ff[j]) + aF0[j] + aF1[j]);
      float cj = tanh_(bf2f(zz[j]) + aC0[j] + aC1[j]);
      hc[j] = fj*hc[j] + (1.f - fj)*cj;
    }
    loadbuf(st+2, z4, f4, r4);   // reissue prefetch (buf fully consumed)
    if (lg < 2){
      #pragma unroll
      for(int j=0;j<4;++j){
        int b = 4*lg + j;
        unsigned short hb = f2bf(hc[j]);
        h_a[b][col] = hb;
        hs[(((size_t)b*Ssz + st) << 10) + h*Dsz + col] = hb;
      }
    }
    asm volatile("s_waitcnt lgkmcnt(0)" ::: "memory");
    __builtin_amdgcn_s_barrier();
    asm volatile("" ::: "memory");
  };

  for(int st=0; st<Ssz; st+=2){
    body(st,   zA, fA, rA);
    body(st+1, zB, fB, rB);
  }
  if (lg < 2){
    #pragma unroll
    for(int j=0;j<4;++j){
      int b = 4*lg + j;
      hT[b*STATEsz + h*Dsz + col] = hc[j];
    }
  }
}

// ---------------- launch ----------------
// ws layout (bytes):                      size
//   xbf   @ 0          bf16[8192*1024]    16,777,216
//   WiT   @ 16777216   bf16[3072*1024]     6,291,456
//   WoT   @ 23068672   bf16[1024*1024]     2,097,152
//   projT @ 25165824   bf16[8*1024*3*128*8] 50,331,648
//   hs    @ 75497472   bf16[8192*1024]    16,777,216
// total 92,274,688 B
extern "C" void kernel_launch(void* const* d_in, const int* in_sizes, int n_in,
                              void* d_out, int out_size, void* d_ws, size_t ws_size,
                              hipStream_t stream){
  const float* x   = (const float*)d_in[0];
  const float* h0  = (const float*)d_in[1];
  const float* Wi  = (const float*)d_in[2];
  const float* bi  = (const float*)d_in[3];
  const float* Wst = (const float*)d_in[4];
  const float* Wfg = (const float*)d_in[5];
  const float* Wrs = (const float*)d_in[6];
  const float* Wo  = (const float*)d_in[7];
  float* out = (float*)d_out;
  float* hT  = out + (size_t)Bsz*Ssz*1024;

  char* ws = (char*)d_ws;
  unsigned short* xbf   = (unsigned short*)(ws);
  unsigned short* WiT   = (unsigned short*)(ws + 16777216);
  unsigned short* WoT   = (unsigned short*)(ws + 23068672);
  unsigned short* projT = (unsigned short*)(ws + 25165824);
  unsigned short* hsb   = (unsigned short*)(ws + 75497472);

  k_cast_bf16<<<dim3(8192), dim3(256), 0, stream>>>(x, xbf, 2097152);
  k_transpose_bf16<<<dim3(3072/32, 1024/32), dim3(32,8), 0, stream>>>(Wi, WiT, 1024, 3072);
  k_transpose_bf16<<<dim3(1024/32, 1024/32), dim3(32,8), 0, stream>>>(Wo, WoT, 1024, 1024);
  k_gemm<2,true><<<dim3(3072/128, 8192/128), dim3(256), 0, stream>>>(
      xbf, WiT, bi, projT, nullptr, 8192, 3072, 1024);
  k_rnn_mfma<<<dim3(8), dim3(512), 0, stream>>>(projT, h0, Wst, Wfg, Wrs, hsb, hT);
  k_gemm<0,false><<<dim3(1024/128, 8192/128), dim3(256), 0, stream>>>(
      hsb, WoT, nullptr, nullptr, out, 8192, 1024, 1024);
}

// Round 11
// 1072.302 us; speedup vs baseline: 1.8794x; 1.8794x over previous
//
#include <hip/hip_runtime.h>
#include <stdint.h>

// Problem constants (GRU_12764642803875)
#define Bsz 8
#define Ssz 1024
#define STATEsz 1024
#define Hsz 8
#define Dsz 128

typedef float  f32x4  __attribute__((ext_vector_type(4)));
typedef int    i32x4  __attribute__((ext_vector_type(4)));
typedef __bf16 bf16x8 __attribute__((ext_vector_type(8)));

__device__ __forceinline__ unsigned short f2bf(float f){
  unsigned int u = __float_as_uint(f);
  u = u + 0x7FFFu + ((u >> 16) & 1u);   // round-to-nearest-even
  return (unsigned short)(u >> 16);
}
__device__ __forceinline__ float bf2f(unsigned short s){
  return __uint_as_float(((unsigned int)s) << 16);
}
__device__ __forceinline__ float sigmoid_(float x){ return 1.f/(1.f+__expf(-x)); }
__device__ __forceinline__ float tanh_(float x){ return 2.f/(1.f+__expf(-2.f*x)) - 1.f; }

#define MFMA16(a,b,c) __builtin_amdgcn_mfma_f32_16x16x32_bf16((a),(b),(c),0,0,0)
#define BAR() do{ asm volatile("s_waitcnt lgkmcnt(0)" ::: "memory"); \
                  __builtin_amdgcn_s_barrier(); \
                  asm volatile("" ::: "memory"); }while(0)

// ---------------- fp32 -> bf16 cast, 4-wide ----------------
__global__ void k_cast_bf16(const float* __restrict__ in, unsigned short* __restrict__ out, int n4){
  int i = blockIdx.x*blockDim.x + threadIdx.x;
  if (i >= n4) return;
  f32x4 v = ((const f32x4*)in)[i];
  ushort4 o;
  o.x = f2bf(v[0]); o.y = f2bf(v[1]); o.z = f2bf(v[2]); o.w = f2bf(v[3]);
  ((ushort4*)out)[i] = o;
}

// ---------------- fp32 [R][C] -> bf16 [C][R] transpose ----------------
__global__ void k_transpose_bf16(const float* __restrict__ in, unsigned short* __restrict__ out, int R, int C){
  __shared__ float tile[32][33];
  int c0 = blockIdx.x*32, r0 = blockIdx.y*32;
  int tx = threadIdx.x, ty = threadIdx.y;   // block (32,8)
  #pragma unroll
  for (int i=0;i<4;++i) tile[ty+8*i][tx] = in[(size_t)(r0+ty+8*i)*C + c0+tx];
  __syncthreads();
  #pragma unroll
  for (int i=0;i<4;++i) out[(size_t)(c0+ty+8*i)*R + r0+tx] = f2bf(tile[tx][ty+8*i]);
}

// ---------------- bf16 MFMA GEMM: C[M,N] = A[M,K] @ Bt[N,K]^T (+bias) ----------------
// MODE 0: f32 C row-major.  MODE 1: bf16 C row-major.
// MODE 2: bf16 scatter into projT[b][h][t][g][d] (N must be 3072, M = B*S).
template<int MODE, bool BIAS>
__global__ __launch_bounds__(256) void k_gemm(
    const unsigned short* __restrict__ A, const unsigned short* __restrict__ Bt,
    const float* __restrict__ bias, unsigned short* __restrict__ Cb, float* __restrict__ Cf,
    int M, int N, int K){
  __shared__ unsigned short As[128][40];
  __shared__ unsigned short Bs[128][40];
  int t = threadIdx.x;
  int l = t & 63, w = t >> 6, wm = w >> 1, wn = w & 1;
  int m0 = blockIdx.y*128, n0 = blockIdx.x*128;
  f32x4 acc[4][4];
  #pragma unroll
  for(int a=0;a<4;++a)
    #pragma unroll
    for(int b=0;b<4;++b){ acc[a][b][0]=0.f; acc[a][b][1]=0.f; acc[a][b][2]=0.f; acc[a][b][3]=0.f; }
  int lr = l & 15, lk = (l >> 4)*8;
  for(int k0=0;k0<K;k0+=32){
    #pragma unroll
    for(int it=0; it<2; ++it){              // stage 128x32 bf16 for A and Bt
      int idx = t + 256*it, r = idx>>2, q = idx&3;
      i32x4 av = *(const i32x4*)(A  + (size_t)(m0+r)*K + k0 + q*8);
      i32x4 bv = *(const i32x4*)(Bt + (size_t)(n0+r)*K + k0 + q*8);
      *(i32x4*)(&As[r][q*8]) = av;
      *(i32x4*)(&Bs[r][q*8]) = bv;
    }
    __syncthreads();
    bf16x8 af[4], bfv[4];
    #pragma unroll
    for(int mi=0;mi<4;++mi) af[mi]  = *(const bf16x8*)(&As[wm*64+mi*16+lr][lk]);
    #pragma unroll
    for(int ni=0;ni<4;++ni) bfv[ni] = *(const bf16x8*)(&Bs[wn*64+ni*16+lr][lk]);
    #pragma unroll
    for(int mi=0;mi<4;++mi)
      #pragma unroll
      for(int ni=0;ni<4;++ni)
        acc[mi][ni] = MFMA16(af[mi], bfv[ni], acc[mi][ni]);
    __syncthreads();
  }
  // C/D layout: col = lane&15, row = (lane>>4)*4 + j  [m89-verified]
  int cr0 = (l>>4)*4;
  #pragma unroll
  for(int mi=0;mi<4;++mi){
    #pragma unroll
    for(int ni=0;ni<4;++ni){
      int col = n0 + wn*64 + ni*16 + lr;
      float bv = BIAS ? bias[col] : 0.f;
      #pragma unroll
      for(int j=0;j<4;++j){
        int row = m0 + wm*64 + mi*16 + cr0 + j;
        float v = acc[mi][ni][j] + bv;
        if (MODE == 0) Cf[(size_t)row*N + col] = v;
        else if (MODE == 1) Cb[(size_t)row*N + col] = f2bf(v);
        else {
          int b = row >> 10, tt = row & 1023;
          int g = col >> 10, hh = (col >> 7) & 7, d = col & 127;
          size_t idx = ((size_t)((b<<3)+hh)*1024 + tt)*384 + g*128 + d;
          Cb[idx] = f2bf(v);
        }
      }
    }
  }
}

// ---------------- recurrence, VALU: 64 blocks = (b,h), 512 threads ----------------
// thread t: e = t&127 (output col), s = t>>7 (k-slice of 32). Weights in VGPRs (96 f32).
// h owner (t<128) keeps h in a register. 4 raw barriers/step (lgkmcnt only, vmcnt
// never drained in-loop). Reduces wave-split: r on waves 0-1 || f on waves 2-3; c on 0-1.
// Gates: wave g in {0,1,2} loads one dword/step from projT[b][h][t][g][d] (coalesced,
// 768B/block/step), depth-2 reg pipeline, reg->LDS staged one step ahead.
__global__ __launch_bounds__(512, 1) void k_rnn_valu(
    const unsigned short* __restrict__ projT,  // [b][h][t][g][d] bf16 (384/step)
    const float* __restrict__ h0,
    const float* __restrict__ Wst, const float* __restrict__ Wfg, const float* __restrict__ Wrs,
    unsigned short* __restrict__ hs, float* __restrict__ hT){
  const int bid = blockIdx.x;
  const int b = bid >> 3, h = bid & 7;
  const int t = threadIdx.x;
  const int s = t >> 7, e = t & 127;

  __shared__ float h_l[128], rh_l[128], f_l[128];
  __shared__ float parts[3][4][128];
  __shared__ unsigned short gl[2][384];      // [step parity][g*128+d]

  // ---- weights: wX[i] = W[32s+i][e] ----
  float wr[32], wf[32], wsw[32];
  {
    const float* pR = Wrs + h*16384 + (32*s)*128 + e;
    const float* pF = Wfg + h*16384 + (32*s)*128 + e;
    const float* pS = Wst + h*16384 + (32*s)*128 + e;
    #pragma unroll
    for(int i=0;i<32;++i){ wr[i]=pR[i*128]; wf[i]=pF[i*128]; wsw[i]=pS[i*128]; }
  }

  float hreg = 0.f;
  if (t < 128){ hreg = h0[b*STATEsz + h*Dsz + e]; h_l[e] = hreg; }

  // ---- gate pipeline: dword per loader thread (waves 0..2 = gates z,f,r) ----
  const unsigned short* pg = projT + (size_t)bid*Ssz*384;
  const bool ldr = (t < 192);
  unsigned int gA = 0u, gB = 0u;
  if (ldr){
    unsigned int g0 = *(const unsigned int*)(pg + 2*t);        // step 0
    gB = *(const unsigned int*)(pg + 384 + 2*t);               // step 1
    ((unsigned int*)gl[0])[t] = g0;
  }
  __syncthreads();

  // body(st): W holds step st+1 (stage to LDS), I gets step st+2 (issue)
  auto body = [&](int st, unsigned int &W, unsigned int &I){
    // ---- phase 1: r,f partial dots (h broadcast from LDS, b128 reads) ----
    float pr = 0.f, pf = 0.f;
    const f32x4* h4 = (const f32x4*)&h_l[32*s];
    #pragma unroll
    for(int i=0;i<8;++i){
      f32x4 hv = h4[i];
      #pragma unroll
      for(int j=0;j<4;++j){ pr += hv[j]*wr[4*i+j]; pf += hv[j]*wf[4*i+j]; }
    }
    parts[0][s][e] = pr; parts[1][s][e] = pf;
    // stage st+1 gates to LDS (compiler inserts counted vmcnt wait; load is 1 step old),
    // then issue st+2 (no wait)
    if (ldr){
      ((unsigned int*)gl[(st+1)&1])[t] = W;
      if (st+2 < Ssz) I = *(const unsigned int*)(pg + (size_t)(st+2)*384 + 2*t);
    }
    BAR();
    // ---- window A: r-reduce (waves 0-1) || f-reduce (waves 2-3) ----
    if (t < 128){
      float rs = bf2f(gl[st&1][256+e])
               + parts[0][0][e]+parts[0][1][e]+parts[0][2][e]+parts[0][3][e];
      rh_l[e] = sigmoid_(rs) * hreg;
    } else if (t < 256){
      float fs = bf2f(gl[st&1][128+e])
               + parts[1][0][e]+parts[1][1][e]+parts[1][2][e]+parts[1][3][e];
      f_l[e] = sigmoid_(fs);
    }
    BAR();
    // ---- phase 2: candidate partial dot on r*h ----
    float pc = 0.f;
    const f32x4* rh4 = (const f32x4*)&rh_l[32*s];
    #pragma unroll
    for(int i=0;i<8;++i){
      f32x4 rv = rh4[i];
      #pragma unroll
      for(int j=0;j<4;++j) pc += rv[j]*wsw[4*i+j];
    }
    parts[2][s][e] = pc;
    BAR();
    // ---- window B: c-reduce + h update (waves 0-1; h in register) ----
    if (t < 128){
      float cs = bf2f(gl[st&1][e])
               + parts[2][0][e]+parts[2][1][e]+parts[2][2][e]+parts[2][3][e];
      float c = tanh_(cs);
      float f = f_l[e];
      hreg = f*hreg + (1.f - f)*c;
      h_l[e] = hreg;
      hs[(((size_t)b*Ssz + st) << 10) + h*Dsz + e] = f2bf(hreg);
    }
    BAR();
  };

  for(int st=0; st<Ssz; st+=2){
    body(st,   gB, gA);
    body(st+1, gA, gB);
  }
  if (t < 128) hT[b*STATEsz + h*Dsz + e] = hreg;
}

// ---------------- launch ----------------
// ws layout (bytes):                      size
//   xbf   @ 0          bf16[8192*1024]    16,777,216
//   WiT   @ 16777216   bf16[3072*1024]     6,291,456
//   WoT   @ 23068672   bf16[1024*1024]     2,097,152
//   projT @ 25165824   bf16[8*8*1024*384] 50,331,648
//   hs    @ 75497472   bf16[8192*1024]    16,777,216
// total 92,274,688 B
extern "C" void kernel_launch(void* const* d_in, const int* in_sizes, int n_in,
                              void* d_out, int out_size, void* d_ws, size_t ws_size,
                              hipStream_t stream){
  const float* x   = (const float*)d_in[0];
  const float* h0  = (const float*)d_in[1];
  const float* Wi  = (const float*)d_in[2];
  const float* bi  = (const float*)d_in[3];
  const float* Wst = (const float*)d_in[4];
  const float* Wfg = (const float*)d_in[5];
  const float* Wrs = (const float*)d_in[6];
  const float* Wo  = (const float*)d_in[7];
  float* out = (float*)d_out;
  float* hT  = out + (size_t)Bsz*Ssz*1024;

  char* ws = (char*)d_ws;
  unsigned short* xbf   = (unsigned short*)(ws);
  unsigned short* WiT   = (unsigned short*)(ws + 16777216);
  unsigned short* WoT   = (unsigned short*)(ws + 23068672);
  unsigned short* projT = (unsigned short*)(ws + 25165824);
  unsigned short* hsb   = (unsigned short*)(ws + 75497472);

  k_cast_bf16<<<dim3(8192), dim3(256), 0, stream>>>(x, xbf, 2097152);
  k_transpose_bf16<<<dim3(3072/32, 1024/32), dim3(32,8), 0, stream>>>(Wi, WiT, 1024, 3072);
  k_transpose_bf16<<<dim3(1024/32, 1024/32), dim3(32,8), 0, stream>>>(Wo, WoT, 1024, 1024);
  k_gemm<2,true><<<dim3(3072/128, 8192/128), dim3(256), 0, stream>>>(
      xbf, WiT, bi, projT, nullptr, 8192, 3072, 1024);
  k_rnn_valu<<<dim3(64), dim3(512), 0, stream>>>(projT, h0, Wst, Wfg, Wrs, hsb, hT);
  k_gemm<0,false><<<dim3(1024/128, 8192/128), dim3(256), 0, stream>>>(
      hsb, WoT, nullptr, nullptr, out, 8192, 1024, 1024);
}